// Round 8
// baseline (494.500 us; speedup 1.0000x reference)
//
#include <hip/hip_runtime.h>
#include <hip/hip_fp16.h>

// GCN: 3x GCNConv(128) + classifier(40) on N=50000, E=800000.
// CSR per call (rank-split) + degree-sorted node permutation (counting sort);
// per layer: fp16 MFMA GEMM (32x32x16, XOR-swizzled 64KB LDS, dinv-scaled
// fp16 epilogue) -> gather-aggregate over fp16 table (4 nodes/wave, 16B/lane,
// 8-deep ILP, fp32 accumulation, degree-balanced waves). Separate classifier.

#define FEAT 128

typedef _Float16 half_t;
typedef _Float16 f16x8 __attribute__((ext_vector_type(8)));
typedef float f32x16 __attribute__((ext_vector_type(16)));
typedef unsigned int u32x4 __attribute__((ext_vector_type(4)));

// ---------------- prep: W transpose->fp16 + zero deg/hist ----------------

__global__ __launch_bounds__(256) void k_prep(const float* __restrict__ W1,
                                              const float* __restrict__ W2,
                                              const float* __restrict__ W3,
                                              half_t* __restrict__ Wt1,
                                              half_t* __restrict__ Wt2,
                                              half_t* __restrict__ Wt3,
                                              int* __restrict__ deg,
                                              int* __restrict__ hist,
                                              int* __restrict__ histCnt, int N) {
  int idx = blockIdx.x * 256 + threadIdx.x;
  if (idx < N) deg[idx] = 0;
  if (idx < 256) { hist[idx] = 0; histCnt[idx] = 0; }
  if (idx < 3 * 16384) {
    int which = idx >> 14;
    int i = idx & 16383;
    int k = i >> 7, n = i & 127;
    const float* W = (which == 0) ? W1 : (which == 1) ? W2 : W3;
    half_t* Wt = (which == 0) ? Wt1 : (which == 1) ? Wt2 : Wt3;
    Wt[n * 128 + k] = (half_t)W[i];
  }
}

// ---------------- CSR build ----------------

// deg count + per-edge rank (atomic return); rank streamed out nontemporal
__global__ __launch_bounds__(256) void k_count_rank(const int* __restrict__ dst,
                                                    int* __restrict__ deg,
                                                    int* __restrict__ rank, int E) {
  int e = blockIdx.x * 256 + threadIdx.x;
  if (e < E) {
    int r = atomicAdd(&deg[dst[e]], 1);
    __builtin_nontemporal_store(r, &rank[e]);
  }
}

// per-block sums for offsets scan + degree histogram (descending-bin)
__global__ __launch_bounds__(256) void k_scanA(const int* __restrict__ deg,
                                               int* __restrict__ partial,
                                               int* __restrict__ hist, int N) {
  __shared__ int s[256];
  int t = threadIdx.x;
  int i = blockIdx.x * 256 + t;
  int v = (i < N) ? deg[i] : 0;
  s[t] = v;
  if (i < N) atomicAdd(&hist[255 - min(v, 255)], 1);
  __syncthreads();
  for (int off = 128; off > 0; off >>= 1) {
    if (t < off) s[t] += s[t + off];
    __syncthreads();
  }
  if (t == 0) partial[blockIdx.x] = s[0];
}

// single block: exclusive scan of hist (256 bins) -> histBase
__global__ __launch_bounds__(256) void k_histscan(const int* __restrict__ hist,
                                                  int* __restrict__ histBase) {
  __shared__ int s[256];
  int t = threadIdx.x;
  int v = hist[t];
  s[t] = v;
  __syncthreads();
  for (int off = 1; off < 256; off <<= 1) {
    int x = (t >= off) ? s[t - off] : 0;
    __syncthreads();
    s[t] += x;
    __syncthreads();
  }
  histBase[t] = s[t] - v;  // exclusive
}

// fused: per-block base from partials (uniform scalar loop) + in-block scan
// + dinv + offsets[N] + degree-sort permutation scatter
__global__ __launch_bounds__(256) void k_scanC2(const int* __restrict__ deg,
                                                const int* __restrict__ partial,
                                                int* __restrict__ offsets,
                                                float* __restrict__ dinv,
                                                const int* __restrict__ histBase,
                                                int* __restrict__ histCnt,
                                                int* __restrict__ perm, int N) {
  __shared__ int s[256];
  int t = threadIdx.x;
  int i = blockIdx.x * 256 + t;
  int base = 0;
  for (int j = 0; j < blockIdx.x; ++j) base += partial[j];  // uniform -> scalar
  int v = (i < N) ? deg[i] : 0;
  s[t] = v;
  __syncthreads();
  for (int off = 1; off < 256; off <<= 1) {
    int x = (t >= off) ? s[t - off] : 0;
    __syncthreads();
    s[t] += x;
    __syncthreads();
  }
  if (i < N) {
    offsets[i] = base + s[t] - v;          // exclusive
    dinv[i] = rsqrtf((float)(v + 1));      // +1 = self loop
    if (i == N - 1) offsets[N] = base + s[t];
    int b = 255 - min(v, 255);             // descending degree order
    int pos = histBase[b] + atomicAdd(&histCnt[b], 1);
    perm[pos] = i;
  }
}

// no atomics: position = offsets[dst] + rank (from count pass)
__global__ __launch_bounds__(256) void k_place(const int* __restrict__ src,
                                               const int* __restrict__ dst,
                                               const int* __restrict__ offsets,
                                               const int* __restrict__ rank,
                                               int* __restrict__ col, int E) {
  int e = blockIdx.x * 256 + threadIdx.x;
  if (e < E) {
    int r = __builtin_nontemporal_load(&rank[e]);
    col[offsets[dst[e]] + r] = src[e];
  }
}

// ---------------- MFMA GEMM ----------------
// T[r][c] = half( dinv[r] * sum_k A[r][k]*W[k][c] ).  128-row tile, full Wt
// in LDS (XOR swizzle byte ^= (row&15)<<4 -> conflict-free b128 frag reads).
// 256 threads = 4 waves; wave computes 32 rows x 128 cols via 32x32x16 MFMA.
template <int SRC_FP32>
__global__ __launch_bounds__(256) void k_gemm_mfma(const void* __restrict__ Asrc,
                                                   const half_t* __restrict__ Wt,
                                                   const float* __restrict__ dinv,
                                                   half_t* __restrict__ T,
                                                   int nrows) {
  __shared__ char lds[65536];
  char* sA = lds;            // 128 rows x 256 B (fp16), swizzled
  char* sW = lds + 32768;    // 128 cols x 256 B (fp16, [n][k]), swizzled
  int t = threadIdx.x;
  int rowBase = blockIdx.x * 128;
  int rowsHere = min(128, nrows - rowBase);

  // stage Wt (2048 x 16B chunks, coalesced read, swizzled LDS write)
  #pragma unroll
  for (int i = 0; i < 8; ++i) {
    int lin = t + i * 256;
    int r = lin >> 4, c = lin & 15;
    *(float4*)(sW + r * 256 + ((c * 16) ^ ((r & 15) << 4))) =
        *(const float4*)((const char*)Wt + r * 256 + c * 16);
  }
  // stage A
  if (SRC_FP32) {
    const float* Af = (const float*)Asrc;
    #pragma unroll
    for (int i = 0; i < 8; ++i) {
      int lin = t + i * 256;
      int r = lin >> 4, c = lin & 15;
      f16x8 h = {};
      if (r < rowsHere) {
        const float4* p = (const float4*)(Af + (size_t)(rowBase + r) * FEAT + c * 8);
        float4 v0 = p[0], v1 = p[1];
        h[0] = (half_t)v0.x; h[1] = (half_t)v0.y; h[2] = (half_t)v0.z; h[3] = (half_t)v0.w;
        h[4] = (half_t)v1.x; h[5] = (half_t)v1.y; h[6] = (half_t)v1.z; h[7] = (half_t)v1.w;
      }
      *(f16x8*)(sA + r * 256 + ((c * 16) ^ ((r & 15) << 4))) = h;
    }
  } else {
    const char* Ah = (const char*)Asrc;
    #pragma unroll
    for (int i = 0; i < 8; ++i) {
      int lin = t + i * 256;
      int r = lin >> 4, c = lin & 15;
      float4 v = {};
      if (r < rowsHere) v = *(const float4*)(Ah + (size_t)(rowBase + r) * 256 + c * 16);
      *(float4*)(sA + r * 256 + ((c * 16) ^ ((r & 15) << 4))) = v;
    }
  }
  __syncthreads();

  int wv = t >> 6;           // wave -> rows [wv*32, wv*32+32)
  int l = t & 63;
  int l31 = l & 31;
  int lhi = l >> 5;
  int sw = (l31 & 15) << 4;

  f32x16 acc[4] = {};

  #pragma unroll
  for (int step = 0; step < 8; ++step) {
    int ko = (step * 32 + lhi * 16) ^ sw;  // this lane's k-group byte offset
    f16x8 a  = *(const f16x8*)(sA + (wv * 32 + l31) * 256 + ko);
    f16x8 b0 = *(const f16x8*)(sW + (l31) * 256 + ko);
    f16x8 b1 = *(const f16x8*)(sW + (32 + l31) * 256 + ko);
    f16x8 b2 = *(const f16x8*)(sW + (64 + l31) * 256 + ko);
    f16x8 b3 = *(const f16x8*)(sW + (96 + l31) * 256 + ko);
    acc[0] = __builtin_amdgcn_mfma_f32_32x32x16_f16(a, b0, acc[0], 0, 0, 0);
    acc[1] = __builtin_amdgcn_mfma_f32_32x32x16_f16(a, b1, acc[1], 0, 0, 0);
    acc[2] = __builtin_amdgcn_mfma_f32_32x32x16_f16(a, b2, acc[2], 0, 0, 0);
    acc[3] = __builtin_amdgcn_mfma_f32_32x32x16_f16(a, b3, acc[3], 0, 0, 0);
  }

  // epilogue: C/D layout col=l&31, row=(j&3)+8*(j>>2)+4*(l>>5)
  #pragma unroll
  for (int j = 0; j < 16; ++j) {
    int rloc = wv * 32 + (j & 3) + 8 * (j >> 2) + 4 * lhi;
    if (rloc < rowsHere) {
      int grow = rowBase + rloc;
      float d = dinv[grow];
      #pragma unroll
      for (int n = 0; n < 4; ++n) {
        T[(size_t)grow * FEAT + n * 32 + l31] = (half_t)(acc[n][j] * d);
      }
    }
  }
}

// ---------------- aggregate ----------------
// T8 rows: 256B = 16 u32x4 (fp16). 4 nodes per wave: 16 lanes/node, lane owns
// features {8q..8q+7} (16B loads). 8-deep unroll -> 32 requests/wave in
// flight. Nodes processed in degree-sorted order (perm) -> balanced waves.

__device__ __forceinline__ void acc8(float* a, u32x4 v) {
  unsigned w0 = v[0], w1 = v[1], w2 = v[2], w3 = v[3];
  __half2 p0 = *(__half2*)&w0, p1 = *(__half2*)&w1;
  __half2 p2 = *(__half2*)&w2, p3 = *(__half2*)&w3;
  a[0] += __half2float(p0.x); a[1] += __half2float(p0.y);
  a[2] += __half2float(p1.x); a[3] += __half2float(p1.y);
  a[4] += __half2float(p2.x); a[5] += __half2float(p2.y);
  a[6] += __half2float(p3.x); a[7] += __half2float(p3.y);
}

__device__ __forceinline__ void gather_node(const u32x4* __restrict__ T8,
                                            const int* __restrict__ offsets,
                                            const int* __restrict__ col,
                                            int node, int q, float* a) {
  u32x4 sv = T8[(size_t)node * 16 + q];  // self loop
  {
    unsigned w0 = sv[0], w1 = sv[1], w2 = sv[2], w3 = sv[3];
    __half2 p0 = *(__half2*)&w0, p1 = *(__half2*)&w1;
    __half2 p2 = *(__half2*)&w2, p3 = *(__half2*)&w3;
    a[0] = __half2float(p0.x); a[1] = __half2float(p0.y);
    a[2] = __half2float(p1.x); a[3] = __half2float(p1.y);
    a[4] = __half2float(p2.x); a[5] = __half2float(p2.y);
    a[6] = __half2float(p3.x); a[7] = __half2float(p3.y);
  }
  int e0 = offsets[node], e1 = offsets[node + 1];
  int e = e0;
  for (; e + 8 <= e1; e += 8) {
    int s[8];
    u32x4 v[8];
    #pragma unroll
    for (int u = 0; u < 8; ++u) s[u] = col[e + u];
    #pragma unroll
    for (int u = 0; u < 8; ++u) v[u] = T8[(size_t)s[u] * 16 + q];
    #pragma unroll
    for (int u = 0; u < 8; ++u) acc8(a, v[u]);
  }
  for (; e < e1; ++e) acc8(a, T8[(size_t)col[e] * 16 + q]);
}

// OUTF=0: fp16 activations; OUTF=1: fp32 h output (classifier reads it next).
template <int OUTF>
__global__ __launch_bounds__(256) void k_aggregate(const u32x4* __restrict__ T8,
                                                   const int* __restrict__ offsets,
                                                   const int* __restrict__ col,
                                                   const int* __restrict__ perm,
                                                   const float* __restrict__ dinv,
                                                   const float* __restrict__ bias,
                                                   u32x4* __restrict__ outH,
                                                   float4* __restrict__ outF,
                                                   int N) {
  int t = threadIdx.x;
  int gid = blockIdx.x * 16 + (t >> 4);
  int q = t & 15;
  if (gid >= N) return;
  int node = perm[gid];

  float a[8];
  gather_node(T8, offsets, col, node, q, a);

  float di = dinv[node];
  const float4* b4 = (const float4*)bias;
  float4 bA = b4[2 * q], bB = b4[2 * q + 1];
  float o0 = fmaxf(di * a[0] + bA.x, 0.f);
  float o1 = fmaxf(di * a[1] + bA.y, 0.f);
  float o2 = fmaxf(di * a[2] + bA.z, 0.f);
  float o3 = fmaxf(di * a[3] + bA.w, 0.f);
  float o4 = fmaxf(di * a[4] + bB.x, 0.f);
  float o5 = fmaxf(di * a[5] + bB.y, 0.f);
  float o6 = fmaxf(di * a[6] + bB.z, 0.f);
  float o7 = fmaxf(di * a[7] + bB.w, 0.f);

  if (OUTF) {
    outF[(size_t)node * 32 + 2 * q] = make_float4(o0, o1, o2, o3);
    outF[(size_t)node * 32 + 2 * q + 1] = make_float4(o4, o5, o6, o7);
  } else {
    __half2 h0 = __floats2half2_rn(o0, o1), h1 = __floats2half2_rn(o2, o3);
    __half2 h2 = __floats2half2_rn(o4, o5), h3 = __floats2half2_rn(o6, o7);
    u32x4 o;
    o[0] = *(unsigned*)&h0; o[1] = *(unsigned*)&h1;
    o[2] = *(unsigned*)&h2; o[3] = *(unsigned*)&h3;
    outH[(size_t)node * 16 + q] = o;
  }
}

// ---------------- classifier ----------------
// logits[N,40] = h[N,128] @ Wc[128,40] + bc.  64 nodes/block; thread handles
// 2 nodes x 5 classes from LDS (h staged coalesced, Wc transposed+padded).
__global__ __launch_bounds__(256) void k_classifier(const float* __restrict__ h,
                                                    const float* __restrict__ Wc,
                                                    const float* __restrict__ bc,
                                                    float* __restrict__ out, int N) {
  __shared__ float sh[64 * 132];    // [node][k] padded
  __shared__ float sWt[40 * 130];   // [c][k] padded
  int t = threadIdx.x;
  int nodeBase = blockIdx.x * 64;
  int nodesHere = min(64, N - nodeBase);

  for (int i = t; i < FEAT * 40; i += 256) {
    int k = i / 40, c = i - k * 40;
    sWt[c * 130 + k] = Wc[i];
  }
  {
    const float4* H4 = (const float4*)(h + (size_t)nodeBase * FEAT);
    #pragma unroll
    for (int i = 0; i < 8; ++i) {
      int lin = t + i * 256;
      int r = lin >> 5, kc = lin & 31;
      float4 v = make_float4(0.f, 0.f, 0.f, 0.f);
      if (r < nodesHere) v = H4[lin];
      *(float4*)&sh[r * 132 + kc * 4] = v;
    }
  }
  __syncthreads();

  int n0 = (t >> 3) * 2;      // this thread's 2 nodes
  int cg = (t & 7) * 5;       // this thread's 5 classes
  float acc0[5], acc1[5];
  #pragma unroll
  for (int j = 0; j < 5; ++j) { acc0[j] = bc[cg + j]; acc1[j] = acc0[j]; }

  #pragma unroll 4
  for (int k4 = 0; k4 < 32; ++k4) {
    float4 h0 = *(const float4*)&sh[n0 * 132 + k4 * 4];
    float4 h1 = *(const float4*)&sh[(n0 + 1) * 132 + k4 * 4];
    #pragma unroll
    for (int j = 0; j < 5; ++j) {
      float4 w = *(const float4*)&sWt[(cg + j) * 130 + k4 * 4];
      acc0[j] += h0.x * w.x + h0.y * w.y + h0.z * w.z + h0.w * w.w;
      acc1[j] += h1.x * w.x + h1.y * w.y + h1.z * w.z + h1.w * w.w;
    }
  }

  if (n0 < nodesHere) {
    float* o = out + (size_t)(nodeBase + n0) * 40 + cg;
    #pragma unroll
    for (int j = 0; j < 5; ++j) o[j] = acc0[j];
  }
  if (n0 + 1 < nodesHere) {
    float* o = out + (size_t)(nodeBase + n0 + 1) * 40 + cg;
    #pragma unroll
    for (int j = 0; j < 5; ++j) o[j] = acc1[j];
  }
}

// ---------------- launch ----------------

extern "C" void kernel_launch(void* const* d_in, const int* in_sizes, int n_in,
                              void* d_out, int out_size, void* d_ws, size_t ws_size,
                              hipStream_t stream) {
  const float* x    = (const float*)d_in[0];
  const int*   edge = (const int*)d_in[1];
  const float* W1   = (const float*)d_in[2];
  const float* b1   = (const float*)d_in[3];
  const float* W2   = (const float*)d_in[4];
  const float* b2   = (const float*)d_in[5];
  const float* W3   = (const float*)d_in[6];
  const float* b3   = (const float*)d_in[7];
  const float* Wc   = (const float*)d_in[8];
  const float* bc   = (const float*)d_in[9];

  int N = in_sizes[0] / FEAT;
  int E = in_sizes[1] / 2;

  float* out  = (float*)d_out;
  float* hOut = out + (size_t)N * 40;  // second output; layer-3 aggregate writes it

  size_t o = 0;
  char* wsb = (char*)d_ws;
  auto take = [&](size_t bytes) -> void* {
    void* p = wsb + o;
    o += (bytes + 255) & ~(size_t)255;
    return p;
  };
  float*   dinv     = (float*)take((size_t)N * 4);
  int*     deg      = (int*)take((size_t)N * 4);
  int*     rank     = (int*)take((size_t)E * 4);
  int*     partial  = (int*)take(256 * 4);
  int*     hist     = (int*)take(256 * 4);
  int*     histBase = (int*)take(256 * 4);
  int*     histCnt  = (int*)take(256 * 4);
  int*     offsets  = (int*)take(((size_t)N + 8) * 4);
  int*     perm     = (int*)take((size_t)N * 4);
  int*     col      = (int*)take((size_t)E * 4);
  half_t*  T2h      = (half_t*)take((size_t)N * FEAT * 2);  // fp16 dinv-scaled h@W
  half_t*  Bh       = (half_t*)take((size_t)N * FEAT * 2);  // fp16 activations
  half_t*  Wt1      = (half_t*)take(16384 * 2);
  half_t*  Wt2      = (half_t*)take(16384 * 2);
  half_t*  Wt3      = (half_t*)take(16384 * 2);

  const int* e_src = edge;
  const int* e_dst = edge + E;

  int nblk = (N + 255) / 256;
  int eblk = (E + 255) / 256;

  k_prep<<<nblk, 256, 0, stream>>>(W1, W2, W3, Wt1, Wt2, Wt3, deg, hist, histCnt, N);
  k_count_rank<<<eblk, 256, 0, stream>>>(e_dst, deg, rank, E);
  k_scanA<<<nblk, 256, 0, stream>>>(deg, partial, hist, N);
  k_histscan<<<1, 256, 0, stream>>>(hist, histBase);
  k_scanC2<<<nblk, 256, 0, stream>>>(deg, partial, offsets, dinv, histBase,
                                     histCnt, perm, N);
  k_place<<<eblk, 256, 0, stream>>>(e_src, e_dst, offsets, rank, col, E);

  int gblk = (N + 127) / 128;
  int ablk = (N + 15) / 16;
  u32x4* T8 = (u32x4*)T2h;
  // layer 1 (fp32 input)
  k_gemm_mfma<1><<<gblk, 256, 0, stream>>>(x, Wt1, dinv, T2h, N);
  k_aggregate<0><<<ablk, 256, 0, stream>>>(T8, offsets, col, perm, dinv, b1,
                                           (u32x4*)Bh, nullptr, N);
  // layer 2 (fp16 input)
  k_gemm_mfma<0><<<gblk, 256, 0, stream>>>(Bh, Wt2, dinv, T2h, N);
  k_aggregate<0><<<ablk, 256, 0, stream>>>(T8, offsets, col, perm, dinv, b2,
                                           (u32x4*)Bh, nullptr, N);
  // layer 3 -> fp32 h output region
  k_gemm_mfma<0><<<gblk, 256, 0, stream>>>(Bh, Wt3, dinv, T2h, N);
  k_aggregate<1><<<ablk, 256, 0, stream>>>(T8, offsets, col, perm, dinv, b3,
                                           nullptr, (float4*)hOut, N);
  // classifier head
  k_classifier<<<(N + 63) / 64, 256, 0, stream>>>(hOut, Wc, bc, out, N);
}

// Round 9
// 240.478 us; speedup vs baseline: 2.0563x; 2.0563x over previous
//
#include <hip/hip_runtime.h>
#include <hip/hip_fp16.h>

// GCN: 3x GCNConv(128) + classifier(40) on N=50000, E=800000.
// Best-known composite: CSR per call (rank-split, fused scans, NO histogram);
// per layer: fp16 MFMA GEMM (32x32x16, full-W 64KB XOR-swizzled LDS,
// dinv-scaled fp16 epilogue) -> gather-aggregate over fp16 table
// (4 nodes/wave, 16B/lane, 8-deep ILP, fp32 accumulation). Separate classifier.

#define FEAT 128

typedef _Float16 half_t;
typedef _Float16 f16x8 __attribute__((ext_vector_type(8)));
typedef float f32x16 __attribute__((ext_vector_type(16)));
typedef unsigned int u32x4 __attribute__((ext_vector_type(4)));

// ---------------- prep: W transpose->fp16 + deg zero (replaces memset) ----------------

__global__ __launch_bounds__(256) void k_prep(const float* __restrict__ W1,
                                              const float* __restrict__ W2,
                                              const float* __restrict__ W3,
                                              half_t* __restrict__ Wt1,
                                              half_t* __restrict__ Wt2,
                                              half_t* __restrict__ Wt3,
                                              int* __restrict__ deg, int N) {
  int idx = blockIdx.x * 256 + threadIdx.x;
  if (idx < N) deg[idx] = 0;
  if (idx < 3 * 16384) {
    int which = idx >> 14;
    int i = idx & 16383;
    int k = i >> 7, n = i & 127;
    const float* W = (which == 0) ? W1 : (which == 1) ? W2 : W3;
    half_t* Wt = (which == 0) ? Wt1 : (which == 1) ? Wt2 : Wt3;
    Wt[n * 128 + k] = (half_t)W[i];
  }
}

// ---------------- CSR build ----------------

// deg count + per-edge rank (atomic return); rank streamed out nontemporal
__global__ __launch_bounds__(256) void k_count_rank(const int* __restrict__ dst,
                                                    int* __restrict__ deg,
                                                    int* __restrict__ rank, int E) {
  int e = blockIdx.x * 256 + threadIdx.x;
  if (e < E) {
    int r = atomicAdd(&deg[dst[e]], 1);
    __builtin_nontemporal_store(r, &rank[e]);
  }
}

__global__ __launch_bounds__(256) void k_scanA(const int* __restrict__ deg,
                                               int* __restrict__ partial, int N) {
  __shared__ int s[256];
  int t = threadIdx.x;
  int i = blockIdx.x * 256 + t;
  s[t] = (i < N) ? deg[i] : 0;
  __syncthreads();
  for (int off = 128; off > 0; off >>= 1) {
    if (t < off) s[t] += s[t + off];
    __syncthreads();
  }
  if (t == 0) partial[blockIdx.x] = s[0];
}

// fused: per-block base from partials (uniform scalar loop) + in-block scan
// + dinv + offsets[N]
__global__ __launch_bounds__(256) void k_scanC2(const int* __restrict__ deg,
                                                const int* __restrict__ partial,
                                                int* __restrict__ offsets,
                                                float* __restrict__ dinv, int N) {
  __shared__ int s[256];
  int t = threadIdx.x;
  int i = blockIdx.x * 256 + t;
  int base = 0;
  for (int j = 0; j < blockIdx.x; ++j) base += partial[j];  // uniform -> scalar
  int v = (i < N) ? deg[i] : 0;
  s[t] = v;
  __syncthreads();
  for (int off = 1; off < 256; off <<= 1) {
    int x = (t >= off) ? s[t - off] : 0;
    __syncthreads();
    s[t] += x;
    __syncthreads();
  }
  if (i < N) {
    offsets[i] = base + s[t] - v;          // exclusive
    dinv[i] = rsqrtf((float)(v + 1));      // +1 = self loop
    if (i == N - 1) offsets[N] = base + s[t];
  }
}

// no atomics: position = offsets[dst] + rank (from count pass)
__global__ __launch_bounds__(256) void k_place(const int* __restrict__ src,
                                               const int* __restrict__ dst,
                                               const int* __restrict__ offsets,
                                               const int* __restrict__ rank,
                                               int* __restrict__ col, int E) {
  int e = blockIdx.x * 256 + threadIdx.x;
  if (e < E) {
    int r = __builtin_nontemporal_load(&rank[e]);
    col[offsets[dst[e]] + r] = src[e];
  }
}

// ---------------- MFMA GEMM ----------------
// T[r][c] = half( dinv[r] * sum_k A[r][k]*W[k][c] ).  128-row tile, full Wt
// in LDS (XOR swizzle byte ^= (row&15)<<4 -> conflict-free b128 frag reads).
// 256 threads = 4 waves; wave computes 32 rows x 128 cols via 32x32x16 MFMA.
template <int SRC_FP32>
__global__ __launch_bounds__(256) void k_gemm_mfma(const void* __restrict__ Asrc,
                                                   const half_t* __restrict__ Wt,
                                                   const float* __restrict__ dinv,
                                                   half_t* __restrict__ T,
                                                   int nrows) {
  __shared__ char lds[65536];
  char* sA = lds;            // 128 rows x 256 B (fp16), swizzled
  char* sW = lds + 32768;    // 128 cols x 256 B (fp16, [n][k]), swizzled
  int t = threadIdx.x;
  int rowBase = blockIdx.x * 128;
  int rowsHere = min(128, nrows - rowBase);

  // stage Wt (2048 x 16B chunks, coalesced read, swizzled LDS write)
  #pragma unroll
  for (int i = 0; i < 8; ++i) {
    int lin = t + i * 256;
    int r = lin >> 4, c = lin & 15;
    *(float4*)(sW + r * 256 + ((c * 16) ^ ((r & 15) << 4))) =
        *(const float4*)((const char*)Wt + r * 256 + c * 16);
  }
  // stage A
  if (SRC_FP32) {
    const float* Af = (const float*)Asrc;
    #pragma unroll
    for (int i = 0; i < 8; ++i) {
      int lin = t + i * 256;
      int r = lin >> 4, c = lin & 15;
      f16x8 h = {};
      if (r < rowsHere) {
        const float4* p = (const float4*)(Af + (size_t)(rowBase + r) * FEAT + c * 8);
        float4 v0 = p[0], v1 = p[1];
        h[0] = (half_t)v0.x; h[1] = (half_t)v0.y; h[2] = (half_t)v0.z; h[3] = (half_t)v0.w;
        h[4] = (half_t)v1.x; h[5] = (half_t)v1.y; h[6] = (half_t)v1.z; h[7] = (half_t)v1.w;
      }
      *(f16x8*)(sA + r * 256 + ((c * 16) ^ ((r & 15) << 4))) = h;
    }
  } else {
    const char* Ah = (const char*)Asrc;
    #pragma unroll
    for (int i = 0; i < 8; ++i) {
      int lin = t + i * 256;
      int r = lin >> 4, c = lin & 15;
      float4 v = {};
      if (r < rowsHere) v = *(const float4*)(Ah + (size_t)(rowBase + r) * 256 + c * 16);
      *(float4*)(sA + r * 256 + ((c * 16) ^ ((r & 15) << 4))) = v;
    }
  }
  __syncthreads();

  int wv = t >> 6;           // wave -> rows [wv*32, wv*32+32)
  int l = t & 63;
  int l31 = l & 31;
  int lhi = l >> 5;
  int sw = (l31 & 15) << 4;

  f32x16 acc[4] = {};

  #pragma unroll
  for (int step = 0; step < 8; ++step) {
    int ko = (step * 32 + lhi * 16) ^ sw;  // this lane's k-group byte offset
    f16x8 a  = *(const f16x8*)(sA + (wv * 32 + l31) * 256 + ko);
    f16x8 b0 = *(const f16x8*)(sW + (l31) * 256 + ko);
    f16x8 b1 = *(const f16x8*)(sW + (32 + l31) * 256 + ko);
    f16x8 b2 = *(const f16x8*)(sW + (64 + l31) * 256 + ko);
    f16x8 b3 = *(const f16x8*)(sW + (96 + l31) * 256 + ko);
    acc[0] = __builtin_amdgcn_mfma_f32_32x32x16_f16(a, b0, acc[0], 0, 0, 0);
    acc[1] = __builtin_amdgcn_mfma_f32_32x32x16_f16(a, b1, acc[1], 0, 0, 0);
    acc[2] = __builtin_amdgcn_mfma_f32_32x32x16_f16(a, b2, acc[2], 0, 0, 0);
    acc[3] = __builtin_amdgcn_mfma_f32_32x32x16_f16(a, b3, acc[3], 0, 0, 0);
  }

  // epilogue: C/D layout col=l&31, row=(j&3)+8*(j>>2)+4*(l>>5)
  #pragma unroll
  for (int j = 0; j < 16; ++j) {
    int rloc = wv * 32 + (j & 3) + 8 * (j >> 2) + 4 * lhi;
    if (rloc < rowsHere) {
      int grow = rowBase + rloc;
      float d = dinv[grow];
      #pragma unroll
      for (int n = 0; n < 4; ++n) {
        T[(size_t)grow * FEAT + n * 32 + l31] = (half_t)(acc[n][j] * d);
      }
    }
  }
}

// ---------------- aggregate ----------------
// T8 rows: 256B = 16 u32x4 (fp16). 4 nodes per wave: 16 lanes/node, lane owns
// features {8q..8q+7} (16B loads). 8-deep unroll -> 32 requests/wave in flight.

__device__ __forceinline__ void acc8(float* a, u32x4 v) {
  unsigned w0 = v[0], w1 = v[1], w2 = v[2], w3 = v[3];
  __half2 p0 = *(__half2*)&w0, p1 = *(__half2*)&w1;
  __half2 p2 = *(__half2*)&w2, p3 = *(__half2*)&w3;
  a[0] += __half2float(p0.x); a[1] += __half2float(p0.y);
  a[2] += __half2float(p1.x); a[3] += __half2float(p1.y);
  a[4] += __half2float(p2.x); a[5] += __half2float(p2.y);
  a[6] += __half2float(p3.x); a[7] += __half2float(p3.y);
}

__device__ __forceinline__ void gather_node(const u32x4* __restrict__ T8,
                                            const int* __restrict__ offsets,
                                            const int* __restrict__ col,
                                            int node, int q, float* a) {
  u32x4 sv = T8[(size_t)node * 16 + q];  // self loop
  {
    unsigned w0 = sv[0], w1 = sv[1], w2 = sv[2], w3 = sv[3];
    __half2 p0 = *(__half2*)&w0, p1 = *(__half2*)&w1;
    __half2 p2 = *(__half2*)&w2, p3 = *(__half2*)&w3;
    a[0] = __half2float(p0.x); a[1] = __half2float(p0.y);
    a[2] = __half2float(p1.x); a[3] = __half2float(p1.y);
    a[4] = __half2float(p2.x); a[5] = __half2float(p2.y);
    a[6] = __half2float(p3.x); a[7] = __half2float(p3.y);
  }
  int e0 = offsets[node], e1 = offsets[node + 1];
  int e = e0;
  for (; e + 8 <= e1; e += 8) {
    int s[8];
    u32x4 v[8];
    #pragma unroll
    for (int u = 0; u < 8; ++u) s[u] = col[e + u];
    #pragma unroll
    for (int u = 0; u < 8; ++u) v[u] = T8[(size_t)s[u] * 16 + q];
    #pragma unroll
    for (int u = 0; u < 8; ++u) acc8(a, v[u]);
  }
  for (; e < e1; ++e) acc8(a, T8[(size_t)col[e] * 16 + q]);
}

// OUTF=0: fp16 activations; OUTF=1: fp32 h output (classifier reads it next).
template <int OUTF>
__global__ __launch_bounds__(256) void k_aggregate(const u32x4* __restrict__ T8,
                                                   const int* __restrict__ offsets,
                                                   const int* __restrict__ col,
                                                   const float* __restrict__ dinv,
                                                   const float* __restrict__ bias,
                                                   u32x4* __restrict__ outH,
                                                   float4* __restrict__ outF,
                                                   int N) {
  int t = threadIdx.x;
  int node = blockIdx.x * 16 + (t >> 4);
  int q = t & 15;
  if (node >= N) return;

  float a[8];
  gather_node(T8, offsets, col, node, q, a);

  float di = dinv[node];
  const float4* b4 = (const float4*)bias;
  float4 bA = b4[2 * q], bB = b4[2 * q + 1];
  float o0 = fmaxf(di * a[0] + bA.x, 0.f);
  float o1 = fmaxf(di * a[1] + bA.y, 0.f);
  float o2 = fmaxf(di * a[2] + bA.z, 0.f);
  float o3 = fmaxf(di * a[3] + bA.w, 0.f);
  float o4 = fmaxf(di * a[4] + bB.x, 0.f);
  float o5 = fmaxf(di * a[5] + bB.y, 0.f);
  float o6 = fmaxf(di * a[6] + bB.z, 0.f);
  float o7 = fmaxf(di * a[7] + bB.w, 0.f);

  if (OUTF) {
    outF[(size_t)node * 32 + 2 * q] = make_float4(o0, o1, o2, o3);
    outF[(size_t)node * 32 + 2 * q + 1] = make_float4(o4, o5, o6, o7);
  } else {
    __half2 h0 = __floats2half2_rn(o0, o1), h1 = __floats2half2_rn(o2, o3);
    __half2 h2 = __floats2half2_rn(o4, o5), h3 = __floats2half2_rn(o6, o7);
    u32x4 o;
    o[0] = *(unsigned*)&h0; o[1] = *(unsigned*)&h1;
    o[2] = *(unsigned*)&h2; o[3] = *(unsigned*)&h3;
    outH[(size_t)node * 16 + q] = o;
  }
}

// ---------------- classifier ----------------
// logits[N,40] = h[N,128] @ Wc[128,40] + bc.  64 nodes/block; thread handles
// 2 nodes x 5 classes from LDS (h staged coalesced, Wc transposed+padded).
__global__ __launch_bounds__(256) void k_classifier(const float* __restrict__ h,
                                                    const float* __restrict__ Wc,
                                                    const float* __restrict__ bc,
                                                    float* __restrict__ out, int N) {
  __shared__ float sh[64 * 132];    // [node][k] padded
  __shared__ float sWt[40 * 130];   // [c][k] padded
  int t = threadIdx.x;
  int nodeBase = blockIdx.x * 64;
  int nodesHere = min(64, N - nodeBase);

  for (int i = t; i < FEAT * 40; i += 256) {
    int k = i / 40, c = i - k * 40;
    sWt[c * 130 + k] = Wc[i];
  }
  {
    const float4* H4 = (const float4*)(h + (size_t)nodeBase * FEAT);
    #pragma unroll
    for (int i = 0; i < 8; ++i) {
      int lin = t + i * 256;
      int r = lin >> 5, kc = lin & 31;
      float4 v = make_float4(0.f, 0.f, 0.f, 0.f);
      if (r < nodesHere) v = H4[lin];
      *(float4*)&sh[r * 132 + kc * 4] = v;
    }
  }
  __syncthreads();

  int n0 = (t >> 3) * 2;      // this thread's 2 nodes
  int cg = (t & 7) * 5;       // this thread's 5 classes
  float acc0[5], acc1[5];
  #pragma unroll
  for (int j = 0; j < 5; ++j) { acc0[j] = bc[cg + j]; acc1[j] = acc0[j]; }

  #pragma unroll 4
  for (int k4 = 0; k4 < 32; ++k4) {
    float4 h0 = *(const float4*)&sh[n0 * 132 + k4 * 4];
    float4 h1 = *(const float4*)&sh[(n0 + 1) * 132 + k4 * 4];
    #pragma unroll
    for (int j = 0; j < 5; ++j) {
      float4 w = *(const float4*)&sWt[(cg + j) * 130 + k4 * 4];
      acc0[j] += h0.x * w.x + h0.y * w.y + h0.z * w.z + h0.w * w.w;
      acc1[j] += h1.x * w.x + h1.y * w.y + h1.z * w.z + h1.w * w.w;
    }
  }

  if (n0 < nodesHere) {
    float* o = out + (size_t)(nodeBase + n0) * 40 + cg;
    #pragma unroll
    for (int j = 0; j < 5; ++j) o[j] = acc0[j];
  }
  if (n0 + 1 < nodesHere) {
    float* o = out + (size_t)(nodeBase + n0 + 1) * 40 + cg;
    #pragma unroll
    for (int j = 0; j < 5; ++j) o[j] = acc1[j];
  }
}

// ---------------- launch ----------------

extern "C" void kernel_launch(void* const* d_in, const int* in_sizes, int n_in,
                              void* d_out, int out_size, void* d_ws, size_t ws_size,
                              hipStream_t stream) {
  const float* x    = (const float*)d_in[0];
  const int*   edge = (const int*)d_in[1];
  const float* W1   = (const float*)d_in[2];
  const float* b1   = (const float*)d_in[3];
  const float* W2   = (const float*)d_in[4];
  const float* b2   = (const float*)d_in[5];
  const float* W3   = (const float*)d_in[6];
  const float* b3   = (const float*)d_in[7];
  const float* Wc   = (const float*)d_in[8];
  const float* bc   = (const float*)d_in[9];

  int N = in_sizes[0] / FEAT;
  int E = in_sizes[1] / 2;

  float* out  = (float*)d_out;
  float* hOut = out + (size_t)N * 40;  // second output; layer-3 aggregate writes it

  size_t o = 0;
  char* wsb = (char*)d_ws;
  auto take = [&](size_t bytes) -> void* {
    void* p = wsb + o;
    o += (bytes + 255) & ~(size_t)255;
    return p;
  };
  float*   dinv    = (float*)take((size_t)N * 4);
  int*     deg     = (int*)take((size_t)N * 4);
  int*     rank    = (int*)take((size_t)E * 4);
  int*     partial = (int*)take(256 * 4);
  int*     offsets = (int*)take(((size_t)N + 8) * 4);
  int*     col     = (int*)take((size_t)E * 4);
  half_t*  T2h     = (half_t*)take((size_t)N * FEAT * 2);  // fp16 dinv-scaled h@W
  half_t*  Bh      = (half_t*)take((size_t)N * FEAT * 2);  // fp16 activations
  half_t*  Wt1     = (half_t*)take(16384 * 2);
  half_t*  Wt2     = (half_t*)take(16384 * 2);
  half_t*  Wt3     = (half_t*)take(16384 * 2);

  const int* e_src = edge;
  const int* e_dst = edge + E;

  int nblk = (N + 255) / 256;
  int eblk = (E + 255) / 256;

  k_prep<<<nblk, 256, 0, stream>>>(W1, W2, W3, Wt1, Wt2, Wt3, deg, N);
  k_count_rank<<<eblk, 256, 0, stream>>>(e_dst, deg, rank, E);
  k_scanA<<<nblk, 256, 0, stream>>>(deg, partial, N);
  k_scanC2<<<nblk, 256, 0, stream>>>(deg, partial, offsets, dinv, N);
  k_place<<<eblk, 256, 0, stream>>>(e_src, e_dst, offsets, rank, col, E);

  int gblk = (N + 127) / 128;
  int ablk = (N + 15) / 16;
  u32x4* T8 = (u32x4*)T2h;
  // layer 1 (fp32 input)
  k_gemm_mfma<1><<<gblk, 256, 0, stream>>>(x, Wt1, dinv, T2h, N);
  k_aggregate<0><<<ablk, 256, 0, stream>>>(T8, offsets, col, dinv, b1,
                                           (u32x4*)Bh, nullptr, N);
  // layer 2 (fp16 input)
  k_gemm_mfma<0><<<gblk, 256, 0, stream>>>(Bh, Wt2, dinv, T2h, N);
  k_aggregate<0><<<ablk, 256, 0, stream>>>(T8, offsets, col, dinv, b2,
                                           (u32x4*)Bh, nullptr, N);
  // layer 3 -> fp32 h output region
  k_gemm_mfma<0><<<gblk, 256, 0, stream>>>(Bh, Wt3, dinv, T2h, N);
  k_aggregate<1><<<ablk, 256, 0, stream>>>(T8, offsets, col, dinv, b3,
                                           nullptr, (float4*)hOut, N);
  // classifier head
  k_classifier<<<(N + 63) / 64, 256, 0, stream>>>(hOut, Wc, bc, out, N);
}

// Round 10
// 229.329 us; speedup vs baseline: 2.1563x; 1.0486x over previous
//
#include <hip/hip_runtime.h>
#include <hip/hip_fp16.h>

// GCN: 3x GCNConv(128) + classifier(40) on N=50000, E=800000.
// R5-exact structure (best known: 230us) + ushort col (halved edge stream).
// CSR per call (rank-split, separate small scanB); per layer: fp16 MFMA GEMM
// (32x32x16, full-W 64KB XOR-swizzled LDS, dinv-scaled fp16 epilogue) ->
// gather-aggregate over fp16 table (2 nodes/wave, 8B/lane, 8-deep ILP,
// fp32 accumulation). Separate classifier.

#define FEAT 128

typedef _Float16 half_t;
typedef _Float16 f16x8 __attribute__((ext_vector_type(8)));
typedef float f32x16 __attribute__((ext_vector_type(16)));

// ---------------- prep: W transpose->fp16 + deg zero (replaces memset) ----------------

__global__ __launch_bounds__(256) void k_prep(const float* __restrict__ W1,
                                              const float* __restrict__ W2,
                                              const float* __restrict__ W3,
                                              half_t* __restrict__ Wt1,
                                              half_t* __restrict__ Wt2,
                                              half_t* __restrict__ Wt3,
                                              int* __restrict__ deg, int N) {
  int idx = blockIdx.x * 256 + threadIdx.x;
  if (idx < N) deg[idx] = 0;
  if (idx < 3 * 16384) {
    int which = idx >> 14;
    int i = idx & 16383;
    int k = i >> 7, n = i & 127;
    const float* W = (which == 0) ? W1 : (which == 1) ? W2 : W3;
    half_t* Wt = (which == 0) ? Wt1 : (which == 1) ? Wt2 : Wt3;
    Wt[n * 128 + k] = (half_t)W[i];
  }
}

// ---------------- CSR build ----------------

// deg count + per-edge rank (atomic return); stores have no dependent consumer
__global__ __launch_bounds__(256) void k_count_rank(const int* __restrict__ dst,
                                                    int* __restrict__ deg,
                                                    int* __restrict__ rank, int E) {
  int e = blockIdx.x * 256 + threadIdx.x;
  if (e < E) rank[e] = atomicAdd(&deg[dst[e]], 1);
}

__global__ __launch_bounds__(256) void k_scanA(const int* __restrict__ deg,
                                               int* __restrict__ partial, int N) {
  __shared__ int s[256];
  int t = threadIdx.x;
  int i = blockIdx.x * 256 + t;
  s[t] = (i < N) ? deg[i] : 0;
  __syncthreads();
  for (int off = 128; off > 0; off >>= 1) {
    if (t < off) s[t] += s[t + off];
    __syncthreads();
  }
  if (t == 0) partial[blockIdx.x] = s[0];
}

// single block: exclusive scan of per-block sums (nblk <= 256)
__global__ __launch_bounds__(256) void k_scanB(int* __restrict__ partial, int nblk,
                                               int* __restrict__ offsets, int N) {
  __shared__ int s[256];
  int t = threadIdx.x;
  int v = (t < nblk) ? partial[t] : 0;
  s[t] = v;
  __syncthreads();
  for (int off = 1; off < 256; off <<= 1) {
    int x = (t >= off) ? s[t - off] : 0;
    __syncthreads();
    s[t] += x;
    __syncthreads();
  }
  if (t < nblk) partial[t] = s[t] - v;   // exclusive prefix
  if (t == 0) offsets[N] = s[255];       // total == E
}

// per-element exclusive scan + fused dinv
__global__ __launch_bounds__(256) void k_scanC(const int* __restrict__ deg,
                                               const int* __restrict__ partial,
                                               int* __restrict__ offsets,
                                               float* __restrict__ dinv, int N) {
  __shared__ int s[256];
  int t = threadIdx.x;
  int i = blockIdx.x * 256 + t;
  int v = (i < N) ? deg[i] : 0;
  s[t] = v;
  __syncthreads();
  for (int off = 1; off < 256; off <<= 1) {
    int x = (t >= off) ? s[t - off] : 0;
    __syncthreads();
    s[t] += x;
    __syncthreads();
  }
  if (i < N) {
    offsets[i] = partial[blockIdx.x] + s[t] - v;
    dinv[i] = rsqrtf((float)(v + 1));  // +1 = self loop
  }
}

// no atomics: position = offsets[dst] + rank; col stored as ushort (N < 65536)
__global__ __launch_bounds__(256) void k_place(const int* __restrict__ src,
                                               const int* __restrict__ dst,
                                               const int* __restrict__ offsets,
                                               const int* __restrict__ rank,
                                               unsigned short* __restrict__ col,
                                               int E) {
  int e = blockIdx.x * 256 + threadIdx.x;
  if (e < E) col[offsets[dst[e]] + rank[e]] = (unsigned short)src[e];
}

// ---------------- MFMA GEMM ----------------
// T[r][c] = half( dinv[r] * sum_k A[r][k]*W[k][c] ).  128-row tile, full Wt
// in LDS (XOR swizzle byte ^= (row&15)<<4 -> conflict-free b128 frag reads).
// 256 threads = 4 waves; wave computes 32 rows x 128 cols via 32x32x16 MFMA.
template <int SRC_FP32>
__global__ __launch_bounds__(256) void k_gemm_mfma(const void* __restrict__ Asrc,
                                                   const half_t* __restrict__ Wt,
                                                   const float* __restrict__ dinv,
                                                   half_t* __restrict__ T,
                                                   int nrows) {
  __shared__ char lds[65536];
  char* sA = lds;            // 128 rows x 256 B (fp16), swizzled
  char* sW = lds + 32768;    // 128 cols x 256 B (fp16, [n][k]), swizzled
  int t = threadIdx.x;
  int rowBase = blockIdx.x * 128;
  int rowsHere = min(128, nrows - rowBase);

  // stage Wt (2048 x 16B chunks, coalesced read, swizzled LDS write)
  #pragma unroll
  for (int i = 0; i < 8; ++i) {
    int lin = t + i * 256;
    int r = lin >> 4, c = lin & 15;
    *(float4*)(sW + r * 256 + ((c * 16) ^ ((r & 15) << 4))) =
        *(const float4*)((const char*)Wt + r * 256 + c * 16);
  }
  // stage A
  if (SRC_FP32) {
    const float* Af = (const float*)Asrc;
    #pragma unroll
    for (int i = 0; i < 8; ++i) {
      int lin = t + i * 256;
      int r = lin >> 4, c = lin & 15;
      f16x8 h = {};
      if (r < rowsHere) {
        const float4* p = (const float4*)(Af + (size_t)(rowBase + r) * FEAT + c * 8);
        float4 v0 = p[0], v1 = p[1];
        h[0] = (half_t)v0.x; h[1] = (half_t)v0.y; h[2] = (half_t)v0.z; h[3] = (half_t)v0.w;
        h[4] = (half_t)v1.x; h[5] = (half_t)v1.y; h[6] = (half_t)v1.z; h[7] = (half_t)v1.w;
      }
      *(f16x8*)(sA + r * 256 + ((c * 16) ^ ((r & 15) << 4))) = h;
    }
  } else {
    const char* Ah = (const char*)Asrc;
    #pragma unroll
    for (int i = 0; i < 8; ++i) {
      int lin = t + i * 256;
      int r = lin >> 4, c = lin & 15;
      float4 v = {};
      if (r < rowsHere) v = *(const float4*)(Ah + (size_t)(rowBase + r) * 256 + c * 16);
      *(float4*)(sA + r * 256 + ((c * 16) ^ ((r & 15) << 4))) = v;
    }
  }
  __syncthreads();

  int wv = t >> 6;           // wave -> rows [wv*32, wv*32+32)
  int l = t & 63;
  int l31 = l & 31;
  int lhi = l >> 5;
  int sw = (l31 & 15) << 4;

  f32x16 acc[4] = {};

  #pragma unroll
  for (int step = 0; step < 8; ++step) {
    int ko = (step * 32 + lhi * 16) ^ sw;  // this lane's k-group byte offset
    f16x8 a  = *(const f16x8*)(sA + (wv * 32 + l31) * 256 + ko);
    f16x8 b0 = *(const f16x8*)(sW + (l31) * 256 + ko);
    f16x8 b1 = *(const f16x8*)(sW + (32 + l31) * 256 + ko);
    f16x8 b2 = *(const f16x8*)(sW + (64 + l31) * 256 + ko);
    f16x8 b3 = *(const f16x8*)(sW + (96 + l31) * 256 + ko);
    acc[0] = __builtin_amdgcn_mfma_f32_32x32x16_f16(a, b0, acc[0], 0, 0, 0);
    acc[1] = __builtin_amdgcn_mfma_f32_32x32x16_f16(a, b1, acc[1], 0, 0, 0);
    acc[2] = __builtin_amdgcn_mfma_f32_32x32x16_f16(a, b2, acc[2], 0, 0, 0);
    acc[3] = __builtin_amdgcn_mfma_f32_32x32x16_f16(a, b3, acc[3], 0, 0, 0);
  }

  // epilogue: C/D layout col=l&31, row=(j&3)+8*(j>>2)+4*(l>>5)
  // (half-wave stores 64 consecutive bytes per (j,n) -> coalesced)
  #pragma unroll
  for (int j = 0; j < 16; ++j) {
    int rloc = wv * 32 + (j & 3) + 8 * (j >> 2) + 4 * lhi;
    if (rloc < rowsHere) {
      int grow = rowBase + rloc;
      float d = dinv[grow];
      #pragma unroll
      for (int n = 0; n < 4; ++n) {
        T[(size_t)grow * FEAT + n * 32 + l31] = (half_t)(acc[n][j] * d);
      }
    }
  }
}

// ---------------- aggregate ----------------
// T4 rows (256B = 32 uint2 of fp16) pre-scaled by dinv[src]. 2 nodes per wave:
// half-wave (32 lanes) per node, lane owns features {4q..4q+3} (8B loads).
// 8-deep unroll -> 16 outstanding row requests/wave. col is ushort.
template <int OUTF>
__global__ __launch_bounds__(256) void k_aggregate(const uint2* __restrict__ T4,
                                                   const int* __restrict__ offsets,
                                                   const unsigned short* __restrict__ col,
                                                   const float* __restrict__ dinv,
                                                   const float* __restrict__ bias,
                                                   float4* __restrict__ outF,
                                                   uint2* __restrict__ outH,
                                                   int N) {
  int wave = threadIdx.x >> 6;
  int half = (threadIdx.x >> 5) & 1;
  int q = threadIdx.x & 31;              // feature quad index
  int node = (blockIdx.x * 4 + wave) * 2 + half;
  if (node >= N) return;
  int e0 = offsets[node], e1 = offsets[node + 1];

  uint2 sv = T4[(size_t)node * 32 + q];  // self loop
  __half2 h0 = *(__half2*)&sv.x, h1 = *(__half2*)&sv.y;
  float ax = __half2float(h0.x), ay = __half2float(h0.y);
  float az = __half2float(h1.x), aw = __half2float(h1.y);

  int e = e0;
  for (; e + 8 <= e1; e += 8) {
    int s0 = col[e + 0], s1 = col[e + 1], s2 = col[e + 2], s3 = col[e + 3];
    int s4 = col[e + 4], s5 = col[e + 5], s6 = col[e + 6], s7 = col[e + 7];
    uint2 v0 = T4[(size_t)s0 * 32 + q];
    uint2 v1 = T4[(size_t)s1 * 32 + q];
    uint2 v2 = T4[(size_t)s2 * 32 + q];
    uint2 v3 = T4[(size_t)s3 * 32 + q];
    uint2 v4 = T4[(size_t)s4 * 32 + q];
    uint2 v5 = T4[(size_t)s5 * 32 + q];
    uint2 v6 = T4[(size_t)s6 * 32 + q];
    uint2 v7 = T4[(size_t)s7 * 32 + q];
    #pragma unroll
    for (int u = 0; u < 8; ++u) {
      uint2 v = (u == 0) ? v0 : (u == 1) ? v1 : (u == 2) ? v2 : (u == 3) ? v3
              : (u == 4) ? v4 : (u == 5) ? v5 : (u == 6) ? v6 : v7;
      __half2 p0 = *(__half2*)&v.x, p1 = *(__half2*)&v.y;
      ax += __half2float(p0.x); ay += __half2float(p0.y);
      az += __half2float(p1.x); aw += __half2float(p1.y);
    }
  }
  for (; e < e1; ++e) {
    uint2 v = T4[(size_t)col[e] * 32 + q];
    __half2 p0 = *(__half2*)&v.x, p1 = *(__half2*)&v.y;
    ax += __half2float(p0.x); ay += __half2float(p0.y);
    az += __half2float(p1.x); aw += __half2float(p1.y);
  }

  float di = dinv[node];
  float4 b = ((const float4*)bias)[q];
  float ox = fmaxf(di * ax + b.x, 0.f);
  float oy = fmaxf(di * ay + b.y, 0.f);
  float oz = fmaxf(di * az + b.z, 0.f);
  float ow = fmaxf(di * aw + b.w, 0.f);
  if (OUTF) {
    outF[(size_t)node * 32 + q] = make_float4(ox, oy, oz, ow);
  } else {
    uint2 o;
    __half2 t0 = __floats2half2_rn(ox, oy), t1 = __floats2half2_rn(oz, ow);
    o.x = *(unsigned*)&t0; o.y = *(unsigned*)&t1;
    outH[(size_t)node * 32 + q] = o;
  }
}

// ---------------- classifier ----------------
// logits[N,40] = h[N,128] @ Wc[128,40] + bc.  64 nodes/block; thread handles
// 2 nodes x 5 classes from LDS (h staged coalesced, Wc transposed+padded).
__global__ __launch_bounds__(256) void k_classifier(const float* __restrict__ h,
                                                    const float* __restrict__ Wc,
                                                    const float* __restrict__ bc,
                                                    float* __restrict__ out, int N) {
  __shared__ float sh[64 * 132];    // [node][k] padded
  __shared__ float sWt[40 * 130];   // [c][k] padded
  int t = threadIdx.x;
  int nodeBase = blockIdx.x * 64;
  int nodesHere = min(64, N - nodeBase);

  for (int i = t; i < FEAT * 40; i += 256) {
    int k = i / 40, c = i - k * 40;
    sWt[c * 130 + k] = Wc[i];
  }
  {
    const float4* H4 = (const float4*)(h + (size_t)nodeBase * FEAT);
    #pragma unroll
    for (int i = 0; i < 8; ++i) {
      int lin = t + i * 256;
      int r = lin >> 5, kc = lin & 31;
      float4 v = make_float4(0.f, 0.f, 0.f, 0.f);
      if (r < nodesHere) v = H4[lin];
      *(float4*)&sh[r * 132 + kc * 4] = v;
    }
  }
  __syncthreads();

  int n0 = (t >> 3) * 2;      // this thread's 2 nodes
  int cg = (t & 7) * 5;       // this thread's 5 classes
  float acc0[5], acc1[5];
  #pragma unroll
  for (int j = 0; j < 5; ++j) { acc0[j] = bc[cg + j]; acc1[j] = acc0[j]; }

  #pragma unroll 4
  for (int k4 = 0; k4 < 32; ++k4) {
    float4 h0 = *(const float4*)&sh[n0 * 132 + k4 * 4];
    float4 h1 = *(const float4*)&sh[(n0 + 1) * 132 + k4 * 4];
    #pragma unroll
    for (int j = 0; j < 5; ++j) {
      float4 w = *(const float4*)&sWt[(cg + j) * 130 + k4 * 4];
      acc0[j] += h0.x * w.x + h0.y * w.y + h0.z * w.z + h0.w * w.w;
      acc1[j] += h1.x * w.x + h1.y * w.y + h1.z * w.z + h1.w * w.w;
    }
  }

  if (n0 < nodesHere) {
    float* o = out + (size_t)(nodeBase + n0) * 40 + cg;
    #pragma unroll
    for (int j = 0; j < 5; ++j) o[j] = acc0[j];
  }
  if (n0 + 1 < nodesHere) {
    float* o = out + (size_t)(nodeBase + n0 + 1) * 40 + cg;
    #pragma unroll
    for (int j = 0; j < 5; ++j) o[j] = acc1[j];
  }
}

// ---------------- launch ----------------

extern "C" void kernel_launch(void* const* d_in, const int* in_sizes, int n_in,
                              void* d_out, int out_size, void* d_ws, size_t ws_size,
                              hipStream_t stream) {
  const float* x    = (const float*)d_in[0];
  const int*   edge = (const int*)d_in[1];
  const float* W1   = (const float*)d_in[2];
  const float* b1   = (const float*)d_in[3];
  const float* W2   = (const float*)d_in[4];
  const float* b2   = (const float*)d_in[5];
  const float* W3   = (const float*)d_in[6];
  const float* b3   = (const float*)d_in[7];
  const float* Wc   = (const float*)d_in[8];
  const float* bc   = (const float*)d_in[9];

  int N = in_sizes[0] / FEAT;
  int E = in_sizes[1] / 2;

  float* out  = (float*)d_out;
  float* hOut = out + (size_t)N * 40;  // second output; layer-3 aggregate writes it

  size_t o = 0;
  char* wsb = (char*)d_ws;
  auto take = [&](size_t bytes) -> void* {
    void* p = wsb + o;
    o += (bytes + 255) & ~(size_t)255;
    return p;
  };
  float*          dinv    = (float*)take((size_t)N * 4);
  int*            deg     = (int*)take((size_t)N * 4);
  int*            rank    = (int*)take((size_t)E * 4);
  int*            partial = (int*)take(256 * 4);
  int*            offsets = (int*)take(((size_t)N + 8) * 4);
  unsigned short* col     = (unsigned short*)take((size_t)E * 2);
  half_t*         T2h     = (half_t*)take((size_t)N * FEAT * 2);  // fp16 h@W
  half_t*         Bh      = (half_t*)take((size_t)N * FEAT * 2);  // fp16 acts
  half_t*         Wt1     = (half_t*)take(16384 * 2);
  half_t*         Wt2     = (half_t*)take(16384 * 2);
  half_t*         Wt3     = (half_t*)take(16384 * 2);

  const int* e_src = edge;
  const int* e_dst = edge + E;

  int nblk = (N + 255) / 256;
  int eblk = (E + 255) / 256;

  k_prep<<<nblk, 256, 0, stream>>>(W1, W2, W3, Wt1, Wt2, Wt3, deg, N);
  k_count_rank<<<eblk, 256, 0, stream>>>(e_dst, deg, rank, E);
  k_scanA<<<nblk, 256, 0, stream>>>(deg, partial, N);
  k_scanB<<<1, 256, 0, stream>>>(partial, nblk, offsets, N);
  k_scanC<<<nblk, 256, 0, stream>>>(deg, partial, offsets, dinv, N);
  k_place<<<eblk, 256, 0, stream>>>(e_src, e_dst, offsets, rank, col, E);

  int gblk = (N + 127) / 128;
  int ablk = (N + 7) / 8;
  uint2* T4 = (uint2*)T2h;
  // layer 1 (fp32 input)
  k_gemm_mfma<1><<<gblk, 256, 0, stream>>>(x, Wt1, dinv, T2h, N);
  k_aggregate<0><<<ablk, 256, 0, stream>>>(T4, offsets, col, dinv, b1, nullptr,
                                           (uint2*)Bh, N);
  // layer 2 (fp16 input)
  k_gemm_mfma<0><<<gblk, 256, 0, stream>>>(Bh, Wt2, dinv, T2h, N);
  k_aggregate<0><<<ablk, 256, 0, stream>>>(T4, offsets, col, dinv, b2, nullptr,
                                           (uint2*)Bh, N);
  // layer 3 -> fp32 h output region
  k_gemm_mfma<0><<<gblk, 256, 0, stream>>>(Bh, Wt3, dinv, T2h, N);
  k_aggregate<1><<<ablk, 256, 0, stream>>>(T4, offsets, col, dinv, b3,
                                           (float4*)hOut, nullptr, N);
  // classifier head
  k_classifier<<<(N + 63) / 64, 256, 0, stream>>>(hOut, Wc, bc, out, N);
}